// Round 9
// baseline (122.815 us; speedup 1.0000x reference)
//
#include <hip/hip_runtime.h>
#include <math.h>

#define NUM_E   1024
#define ZQ_ELEM 8388608         // 32*64*64*64
#define AGRID   256
#define MAXC    7
#define OQCAP   512

typedef short bf16x8 __attribute__((ext_vector_type(8)));
typedef float f32x16 __attribute__((ext_vector_type(16)));

__device__ inline unsigned short rne_bf16(float v) {
    unsigned u = __float_as_uint(v);
    return (unsigned short)((u + 0x7FFFu + ((u >> 16) & 1u)) >> 16);  // RNE, finite-safe
}

// ---------------------------------------------------------------- prep: ee + bf16-hi B fragments
// B-frag layout for mfma_f32_32x32x16_bf16: lane l holds col j = nt*32+(l&31),
// k = kt*16 + (l>>5)*8 + i.  Packet index = (nt*4+kt)*64 + (l>>5)*32 + (j&31).
__global__ __launch_bounds__(256) void vq_prep(const float* __restrict__ cb,
                                               float* __restrict__ ee,
                                               unsigned short* __restrict__ ehi)
{
    int j = blockIdx.x * 256 + threadIdx.x;   // grid 4 -> 1024 codes
    const float* r = cb + (size_t)j * 64;
    float v[64];
#pragma unroll
    for (int k = 0; k < 64; ++k) v[k] = r[k];
    float a = 0.f;
#pragma unroll
    for (int k = 0; k < 64; ++k) a = fmaf(v[k], v[k], a);   // same chain as r1-r8
    ee[j] = a;

    int nt = j >> 5, jc = j & 31;
#pragma unroll
    for (int kt = 0; kt < 4; ++kt)
#pragma unroll
        for (int h = 0; h < 2; ++h) {
            bf16x8 vh;
#pragma unroll
            for (int i = 0; i < 8; ++i)
                vh[i] = (short)rne_bf16(v[kt * 16 + h * 8 + i]);
            *(bf16x8*)(ehi + ((size_t)(nt * 4 + kt) * 64 + h * 32 + jc) * 8) = vh;
        }
}

// exact d for (own point in registers vv, code j): bit-identical chain to r1-r8
__device__ inline unsigned long long key_regs(const float* vv, float zz, float eej,
                                              const float* cb, int j)
{
    const float4* cr = (const float4*)(cb + ((size_t)j << 6));
    float a = 0.f;
#pragma unroll
    for (int q = 0; q < 16; ++q) {
        float4 c4 = cr[q];
        a = fmaf(vv[4 * q + 0], c4.x, a);
        a = fmaf(vv[4 * q + 1], c4.y, a);
        a = fmaf(vv[4 * q + 2], c4.z, a);
        a = fmaf(vv[4 * q + 3], c4.w, a);
    }
    float t1 = zz + eej;
    float d  = fmaf(-2.f, a, t1);
    return ((unsigned long long)__float_as_uint(d) << 32) | (unsigned long long)j;
}

// same chain, z from global (overflow path only)
__device__ inline unsigned long long key_glob(const float* zb, float zz, float eej,
                                              const float* cb, int pl, int j)
{
    const float4* cr = (const float4*)(cb + ((size_t)j << 6));
    float a = 0.f;
#pragma unroll
    for (int q = 0; q < 16; ++q) {
        float4 c4 = cr[q];
        a = fmaf(zb[(size_t)(4 * q + 0) * 4096 + pl], c4.x, a);
        a = fmaf(zb[(size_t)(4 * q + 1) * 4096 + pl], c4.y, a);
        a = fmaf(zb[(size_t)(4 * q + 2) * 4096 + pl], c4.z, a);
        a = fmaf(zb[(size_t)(4 * q + 3) * 4096 + pl], c4.w, a);
    }
    float t1 = zz + eej;
    float d  = fmaf(-2.f, a, t1);
    return ((unsigned long long)__float_as_uint(d) << 32) | (unsigned long long)j;
}

// ---------------------------------------------------------------- argmin + quant (fused, LDS-resident B)
// Block = 512 threads = 8 waves = 512 points (8 h-rows); grid 256 = 1 block/CU.
// ehi (128 KB) staged into LDS once; both sweeps read B via conflict-free ds_read_b128.
// Each thread holds its point's z in 64 VGPRs -> register-exact refine + tail.
__global__ __launch_bounds__(512, 2) void vq_argmin(
    const float* __restrict__ z, const float* __restrict__ cb,
    const unsigned short* __restrict__ ehi, const float* __restrict__ ee,
    float* __restrict__ idx_f, int* __restrict__ counts,
    float* __restrict__ zq, double* __restrict__ partials)
{
    __shared__ bf16x8 bB[8192];                 // 128 KB: linear copy of ehi
    __shared__ float  eeL[1024];                // 4 KB
    __shared__ float  zzsL[512];                // 2 KB (overflow-path refine)
    __shared__ float  wp[512];                  // 2 KB per-point window
    __shared__ unsigned long long best[512];    // 4 KB
    __shared__ unsigned short cand[512 * MAXC]; // 7 KB per-point candidate lists
    __shared__ unsigned int ccnt[512];          // 2 KB
    __shared__ unsigned int oq[OQCAP];          // 2 KB overflow queue
    __shared__ unsigned int oqcnt, gflow;
    __shared__ double wsum[8];

    const int tid  = threadIdx.x;
    const int g    = blockIdx.x;                // 256 blocks: 8 per image
    const int lane = tid & 63, wv = tid >> 6;
    const size_t zoff = ((size_t)(g >> 3) << 18) + (size_t)((g & 7) << 9);
    const float* zb = z + zoff;

    // ---- init + stage eeL
    best[tid] = 0xFFFFFFFFFFFFFFFFull;
    ccnt[tid] = 0;
    if (tid == 0) { oqcnt = 0; gflow = 0; }
    eeL[tid]       = ee[tid];
    eeL[tid + 512] = ee[tid + 512];

    // ---- stage ehi -> LDS (reg-staged, coalesced, once per block)
    {
        const uint4* src = (const uint4*)ehi;   // 8192 packets of 16 B
        uint4* dst = (uint4*)bB;
#pragma unroll
        for (int pass = 0; pass < 4; ++pass) {
            uint4 a = src[pass * 2048 + tid];
            uint4 b = src[pass * 2048 + 512 + tid];
            uint4 c = src[pass * 2048 + 1024 + tid];
            uint4 d = src[pass * 2048 + 1536 + tid];
            dst[pass * 2048 + tid] = a;
            dst[pass * 2048 + 512 + tid] = b;
            dst[pass * 2048 + 1024 + tid] = c;
            dst[pass * 2048 + 1536 + tid] = d;
        }
    }

    // ---- own point's z into registers; zz with exact 64-chain fmaf order
    float vv[64];
#pragma unroll
    for (int k = 0; k < 64; ++k) vv[k] = zb[(size_t)k * 4096 + tid];
    float zz;
    {
        float a = 0.f;
#pragma unroll
        for (int k = 0; k < 64; ++k) a = fmaf(vv[k], vv[k], a);
        zz = a; zzsL[tid] = a;
    }

    // ---- A-fragments (z-hi) for 2 row-groups + per-point rigorous window
    bf16x8 ah0[4], ah1[4];
    {
        int h = lane >> 5;
#pragma unroll
        for (int g2 = 0; g2 < 2; ++g2) {
            int pl = wv * 64 + g2 * 32 + (lane & 31);
            float s1 = 0.f, sd = 0.f;
#pragma unroll
            for (int kt = 0; kt < 4; ++kt)
#pragma unroll
                for (int i = 0; i < 8; ++i) {
                    int k = kt * 16 + h * 8 + i;
                    float x = zb[(size_t)k * 4096 + pl];
                    unsigned short hb = rne_bf16(x);
                    float hf = __uint_as_float((unsigned)hb << 16);
                    if (g2 == 0) ah0[kt][i] = (short)hb; else ah1[kt][i] = (short)hb;
                    s1 += fabsf(x);
                    sd += fabsf(x - hf);
                }
            s1 += __shfl_xor(s1, 32);
            sd += __shfl_xor(sd, 32);
            // W = 2*eps_data bound (x2 margin) + 4e-5 (d<->s offsets) + 1e-4 margin (r6-r8 formula)
            if (lane < 32) wp[pl] = 4.f * (s1 * 1.907e-6f + sd * 9.785e-4f) + 1.4e-4f;
        }
    }
    __syncthreads();                            // bB/eeL/zzsL/wp visible

    float m0[16], m1[16];
#pragma unroll
    for (int r = 0; r < 16; ++r) { m0[r] = 3.4e38f; m1[r] = 3.4e38f; }

    // ---- sweep 1: per-row min of s~ (B from LDS, barrier-free)
#pragma unroll 2
    for (int nt = 0; nt < 32; ++nt) {
        bf16x8 b0 = bB[(nt * 4 + 0) * 64 + lane];
        bf16x8 b1 = bB[(nt * 4 + 1) * 64 + lane];
        bf16x8 b2 = bB[(nt * 4 + 2) * 64 + lane];
        bf16x8 b3 = bB[(nt * 4 + 3) * 64 + lane];
        float eA = eeL[nt * 32 + (lane & 31)];
        f32x16 a0, a1;
#pragma unroll
        for (int r = 0; r < 16; ++r) { a0[r] = 0.f; a1[r] = 0.f; }
        a0 = __builtin_amdgcn_mfma_f32_32x32x16_bf16(ah0[0], b0, a0, 0, 0, 0);
        a1 = __builtin_amdgcn_mfma_f32_32x32x16_bf16(ah1[0], b0, a1, 0, 0, 0);
        a0 = __builtin_amdgcn_mfma_f32_32x32x16_bf16(ah0[1], b1, a0, 0, 0, 0);
        a1 = __builtin_amdgcn_mfma_f32_32x32x16_bf16(ah1[1], b1, a1, 0, 0, 0);
        a0 = __builtin_amdgcn_mfma_f32_32x32x16_bf16(ah0[2], b2, a0, 0, 0, 0);
        a1 = __builtin_amdgcn_mfma_f32_32x32x16_bf16(ah1[2], b2, a1, 0, 0, 0);
        a0 = __builtin_amdgcn_mfma_f32_32x32x16_bf16(ah0[3], b3, a0, 0, 0, 0);
        a1 = __builtin_amdgcn_mfma_f32_32x32x16_bf16(ah1[3], b3, a1, 0, 0, 0);
#pragma unroll
        for (int r = 0; r < 16; ++r) {
            m0[r] = fminf(m0[r], fmaf(-2.f, a0[r], eA));
            m1[r] = fminf(m1[r], fmaf(-2.f, a1[r], eA));
        }
    }
    // butterfly min across 32 col-lanes, then fold per-point window -> threshold
#pragma unroll
    for (int r = 0; r < 16; ++r) {
        for (int d2 = 1; d2 <= 16; d2 <<= 1) {
            m0[r] = fminf(m0[r], __shfl_xor(m0[r], d2));
            m1[r] = fminf(m1[r], __shfl_xor(m1[r], d2));
        }
        int row = 4 * (lane >> 5) + (r & 3) + 8 * (r >> 2);
        m0[r] += wp[wv * 64 + row];
        m1[r] += wp[wv * 64 + 32 + row];
    }

#define ENQ(PL, JJ) do {                                                  \
    unsigned _s = atomicAdd(&ccnt[PL], 1u);                               \
    if (_s < MAXC) cand[(PL) * MAXC + _s] = (unsigned short)(JJ);         \
    else { unsigned _o = atomicAdd(&oqcnt, 1u);                           \
           if (_o < OQCAP) oq[_o] = ((unsigned)(PL) << 16) | (JJ);        \
           else gflow = 1; }                                              \
} while (0)

    // ---- sweep 2: recompute (bit-identical), enqueue window hits into per-point lists
#pragma unroll 1
    for (int nt = 0; nt < 32; ++nt) {
        bf16x8 b0 = bB[(nt * 4 + 0) * 64 + lane];
        bf16x8 b1 = bB[(nt * 4 + 1) * 64 + lane];
        bf16x8 b2 = bB[(nt * 4 + 2) * 64 + lane];
        bf16x8 b3 = bB[(nt * 4 + 3) * 64 + lane];
        float eA = eeL[nt * 32 + (lane & 31)];
        f32x16 a0, a1;
#pragma unroll
        for (int r = 0; r < 16; ++r) { a0[r] = 0.f; a1[r] = 0.f; }
        a0 = __builtin_amdgcn_mfma_f32_32x32x16_bf16(ah0[0], b0, a0, 0, 0, 0);
        a1 = __builtin_amdgcn_mfma_f32_32x32x16_bf16(ah1[0], b0, a1, 0, 0, 0);
        a0 = __builtin_amdgcn_mfma_f32_32x32x16_bf16(ah0[1], b1, a0, 0, 0, 0);
        a1 = __builtin_amdgcn_mfma_f32_32x32x16_bf16(ah1[1], b1, a1, 0, 0, 0);
        a0 = __builtin_amdgcn_mfma_f32_32x32x16_bf16(ah0[2], b2, a0, 0, 0, 0);
        a1 = __builtin_amdgcn_mfma_f32_32x32x16_bf16(ah1[2], b2, a1, 0, 0, 0);
        a0 = __builtin_amdgcn_mfma_f32_32x32x16_bf16(ah0[3], b3, a0, 0, 0, 0);
        a1 = __builtin_amdgcn_mfma_f32_32x32x16_bf16(ah1[3], b3, a1, 0, 0, 0);
        unsigned jj = (unsigned)(nt * 32 + (lane & 31));
#pragma unroll
        for (int r = 0; r < 16; ++r) {
            int row = 4 * (lane >> 5) + (r & 3) + 8 * (r >> 2);
            bool h0 = fmaf(-2.f, a0[r], eA) <= m0[r];
            if (__any(h0)) { if (h0) { int pl = wv * 64 + row;      ENQ(pl, jj); } }
            bool h1 = fmaf(-2.f, a1[r], eA) <= m1[r];
            if (__any(h1)) { if (h1) { int pl = wv * 64 + 32 + row; ENQ(pl, jj); } }
        }
    }
    __syncthreads();

    // ---- exact refine: own point from registers (+ overflow queue; gflow = brute force)
    if (gflow) {
        unsigned long long bk = 0xFFFFFFFFFFFFFFFFull;
        for (int j = 0; j < NUM_E; ++j) {
            unsigned long long k2 = key_regs(vv, zz, eeL[j], cb, j);
            if (k2 < bk) bk = k2;
        }
        best[tid] = bk;
    } else {
        int n = (int)ccnt[tid]; if (n > MAXC) n = MAXC;
        unsigned long long bk = 0xFFFFFFFFFFFFFFFFull;
        for (int e = 0; e < n; ++e) {
            int j = (int)cand[tid * MAXC + e];
            unsigned long long k2 = key_regs(vv, zz, eeL[j], cb, j);
            if (k2 < bk) bk = k2;
        }
        atomicMin(&best[tid], bk);
        int no = (int)oqcnt; if (no > OQCAP) no = OQCAP;
        for (int e = tid; e < no; e += 512) {
            unsigned u = oq[e];
            int pl = (int)(u >> 16), j = (int)(u & 0xFFFFu);
            atomicMin(&best[pl], key_glob(zb, zzsL[pl], eeL[j], cb, pl, j));
        }
    }
    __syncthreads();

    // ---- outputs: idx, counts, fused tail from registers (coalesced scalar stores)
    {
        int bi = (int)(best[tid] & 0xFFFFFFFFull);
        idx_f[(size_t)g * 512 + tid] = (float)bi;
        atomicAdd(&counts[bi], 1);
        const float* crow = cb + ((size_t)bi << 6);
        float* zqp = zq + zoff + tid;
        double ls = 0.0;
#pragma unroll
        for (int c = 0; c < 64; ++c) {
            float q = crow[c];
            float t = q - vv[c];                 // fl(q - z)
            zqp[(size_t)c * 4096] = vv[c] + t;   // fl(z + t)
            ls += (double)t * t;
        }
#pragma unroll
        for (int off = 32; off > 0; off >>= 1) ls += __shfl_down(ls, off);
        if (lane == 0) wsum[wv] = ls;
    }
    __syncthreads();
    if (tid == 0) {
        double s = 0.0;
#pragma unroll
        for (int i = 0; i < 8; ++i) s += wsum[i];
        partials[g] = s;
    }
}

// ---------------------------------------------------------------- scalars
__global__ __launch_bounds__(256) void vq_final(
    const int* __restrict__ counts, const double* __restrict__ partials,
    float* __restrict__ scalars)
{
    __shared__ double sh[256];
    __shared__ double sl[256];
    int t = threadIdx.x;
    double s = 0.0;
    for (int j = t; j < NUM_E; j += 256) {
        float em   = (float)counts[j] * (1.0f / 131072.0f);
        float term = em * logf(em + 1e-10f);
        s += (double)term;
    }
    double l = 0.0;
#pragma unroll
    for (int j = 0; j < AGRID / 256; ++j) l += partials[j * 256 + t];
    sh[t] = s;
    sl[t] = l;
    __syncthreads();
    for (int off = 128; off > 0; off >>= 1) {
        if (t < off) { sh[t] += sh[t + off]; sl[t] += sl[t + off]; }
        __syncthreads();
    }
    if (t == 0) {
        float mm = (float)(sl[0] / 8388608.0);
        scalars[0] = mm + 0.5f * mm;         // mean1 + BETA*mean2
        scalars[1] = expf(-(float)sh[0]);    // perplexity
    }
}

// ---------------------------------------------------------------- launch
extern "C" void kernel_launch(void* const* d_in, const int* in_sizes, int n_in,
                              void* d_out, int out_size, void* d_ws, size_t ws_size,
                              hipStream_t stream)
{
    const float* z  = (const float*)d_in[0];
    const float* cb = (const float*)d_in[1];
    float* out     = (float*)d_out;
    float* zq      = out;                    // [32,64,64,64]
    float* scalars = out + ZQ_ELEM;          // loss, perplexity
    float* idx_f   = out + ZQ_ELEM + 2;      // [32,64,64] as float

    int*            counts   = (int*)d_ws;                             // 4 KB
    double*         partials = (double*)((char*)d_ws + 4096);          // 2 KB
    float*          ee       = (float*)((char*)d_ws + 12288);          // 4 KB
    unsigned short* ehi      = (unsigned short*)((char*)d_ws + 16384); // 128 KB

    hipMemsetAsync(d_ws, 0, 4096, stream);                    // zero counts
    vq_prep  <<<4,     256, 0, stream>>>(cb, ee, ehi);
    vq_argmin<<<AGRID, 512, 0, stream>>>(z, cb, ehi, ee, idx_f, counts, zq, partials);
    vq_final <<<1,     256, 0, stream>>>(counts, partials, scalars);
}

// Round 10
// 114.116 us; speedup vs baseline: 1.0762x; 1.0762x over previous
//
#include <hip/hip_runtime.h>
#include <math.h>

#define NUM_E   1024
#define ZQ_ELEM 8388608         // 32*64*64*64
#define AGRID   256
#define MAXC    7
#define OQCAP   512

typedef short bf16x8 __attribute__((ext_vector_type(8)));
typedef float f32x16 __attribute__((ext_vector_type(16)));

__device__ inline unsigned short rne_bf16(float v) {
    unsigned u = __float_as_uint(v);
    return (unsigned short)((u + 0x7FFFu + ((u >> 16) & 1u)) >> 16);  // RNE, finite-safe
}

// ---------------------------------------------------------------- prep: ee + bf16-hi B fragments
// B-frag layout for mfma_f32_32x32x16_bf16: lane l holds col j = nt*32+(l&31),
// k = kt*16 + (l>>5)*8 + i.  Packet index = (nt*4+kt)*64 + (l>>5)*32 + (j&31).
__global__ __launch_bounds__(256) void vq_prep(const float* __restrict__ cb,
                                               float* __restrict__ ee,
                                               unsigned short* __restrict__ ehi)
{
    int j = blockIdx.x * 256 + threadIdx.x;   // grid 4 -> 1024 codes
    const float* r = cb + (size_t)j * 64;
    float v[64];
#pragma unroll
    for (int k = 0; k < 64; ++k) v[k] = r[k];
    float a = 0.f;
#pragma unroll
    for (int k = 0; k < 64; ++k) a = fmaf(v[k], v[k], a);   // same chain as r1-r9
    ee[j] = a;

    int nt = j >> 5, jc = j & 31;
#pragma unroll
    for (int kt = 0; kt < 4; ++kt)
#pragma unroll
        for (int h = 0; h < 2; ++h) {
            bf16x8 vh;
#pragma unroll
            for (int i = 0; i < 8; ++i)
                vh[i] = (short)rne_bf16(v[kt * 16 + h * 8 + i]);
            *(bf16x8*)(ehi + ((size_t)(nt * 4 + kt) * 64 + h * 32 + jc) * 8) = vh;
        }
}

// exact d for (point pl, code j), z from global: bit-identical chain to r1-r9
__device__ inline unsigned long long key_glob(const float* zb, float zz, float eej,
                                              const float* cb, int pl, int j)
{
    const float4* cr = (const float4*)(cb + ((size_t)j << 6));
    float a = 0.f;
#pragma unroll
    for (int q = 0; q < 16; ++q) {
        float4 c4 = cr[q];
        a = fmaf(zb[(size_t)(4 * q + 0) * 4096 + pl], c4.x, a);
        a = fmaf(zb[(size_t)(4 * q + 1) * 4096 + pl], c4.y, a);
        a = fmaf(zb[(size_t)(4 * q + 2) * 4096 + pl], c4.z, a);
        a = fmaf(zb[(size_t)(4 * q + 3) * 4096 + pl], c4.w, a);
    }
    float t1 = zz + eej;
    float d  = fmaf(-2.f, a, t1);
    return ((unsigned long long)__float_as_uint(d) << 32) | (unsigned long long)j;
}

// ---------------------------------------------------------------- argmin + quant (fused, LDS-resident B)
// Block = 1024 threads = 16 waves = 512 points; grid 256 -> 1 block/CU, 4 waves/SIMD.
// Wave wv owns rows wv*32..wv*32+31 (one A-group). No long-lived per-thread arrays (no spill).
__global__ __launch_bounds__(1024, 4) void vq_argmin(
    const float* __restrict__ z, const float* __restrict__ cb,
    const unsigned short* __restrict__ ehi, const float* __restrict__ ee,
    float* __restrict__ idx_f, int* __restrict__ counts,
    float* __restrict__ zq, double* __restrict__ partials)
{
    __shared__ bf16x8 bB[8192];                 // 128 KB: linear copy of ehi
    __shared__ float  eeL[1024];                // 4 KB
    __shared__ float  zzs[512];                 // 2 KB
    __shared__ float  wp[512];                  // 2 KB per-point window
    __shared__ unsigned long long best[512];    // 4 KB
    __shared__ unsigned short cand[512 * MAXC]; // 7 KB per-point candidate lists
    __shared__ unsigned int ccnt[512];          // 2 KB
    __shared__ unsigned int oq[OQCAP];          // 2 KB overflow queue
    __shared__ int ibuf[512];                   // 2 KB
    __shared__ unsigned int oqcnt, gflow;
    __shared__ double wsum[16];

    const int tid  = threadIdx.x;
    const int g    = blockIdx.x;                // 256 blocks: 8 per image
    const int lane = tid & 63, wv = tid >> 6;   // wv in [0,16)
    const size_t zoff = ((size_t)(g >> 3) << 18) + (size_t)((g & 7) << 9);
    const float* zb = z + zoff;

    // ---- init + stage eeL + stage bB (coalesced uint4, once per block)
    eeL[tid] = ee[tid];
    if (tid < 512) { best[tid] = 0xFFFFFFFFFFFFFFFFull; ccnt[tid] = 0; }
    if (tid == 0) { oqcnt = 0; gflow = 0; }
    {
        const uint4* src = (const uint4*)ehi;   // 8192 packets of 16 B
        uint4* dst = (uint4*)bB;
#pragma unroll
        for (int i = 0; i < 8; ++i)
            dst[i * 1024 + tid] = src[i * 1024 + tid];
    }

    // ---- zz: exact 64-chain fmaf order (same as r1-r9), coalesced, streaming regs
    if (tid < 512) {
        float a = 0.f;
#pragma unroll
        for (int k = 0; k < 64; ++k) {
            float v = zb[(size_t)k * 4096 + tid];
            a = fmaf(v, v, a);
        }
        zzs[tid] = a;
    }

    // ---- A-fragment (z-hi) + per-point rigorous window (r6-r9 formula)
    bf16x8 ah[4];
    {
        int h = lane >> 5;
        int pl = wv * 32 + (lane & 31);
        float s1 = 0.f, sd = 0.f;
#pragma unroll
        for (int kt = 0; kt < 4; ++kt)
#pragma unroll
            for (int i = 0; i < 8; ++i) {
                int k = kt * 16 + h * 8 + i;
                float x = zb[(size_t)k * 4096 + pl];
                unsigned short hb = rne_bf16(x);
                float hf = __uint_as_float((unsigned)hb << 16);
                ah[kt][i] = (short)hb;
                s1 += fabsf(x);
                sd += fabsf(x - hf);
            }
        s1 += __shfl_xor(s1, 32);
        sd += __shfl_xor(sd, 32);
        // W = 2*eps_data bound (x2 margin) + 4e-5 (d<->s offsets) + 1e-4 margin
        if (lane < 32) wp[pl] = 4.f * (s1 * 1.907e-6f + sd * 9.785e-4f) + 1.4e-4f;
    }
    __syncthreads();                            // bB/eeL/zzs/wp visible

    float m[16];
#pragma unroll
    for (int r = 0; r < 16; ++r) m[r] = 3.4e38f;

    // ---- sweep 1: per-row min of s~ (B from LDS, barrier-free)
#pragma unroll 2
    for (int nt = 0; nt < 32; ++nt) {
        bf16x8 b0 = bB[(nt * 4 + 0) * 64 + lane];
        bf16x8 b1 = bB[(nt * 4 + 1) * 64 + lane];
        bf16x8 b2 = bB[(nt * 4 + 2) * 64 + lane];
        bf16x8 b3 = bB[(nt * 4 + 3) * 64 + lane];
        float eA = eeL[nt * 32 + (lane & 31)];
        f32x16 acc;
#pragma unroll
        for (int r = 0; r < 16; ++r) acc[r] = 0.f;
        acc = __builtin_amdgcn_mfma_f32_32x32x16_bf16(ah[0], b0, acc, 0, 0, 0);
        acc = __builtin_amdgcn_mfma_f32_32x32x16_bf16(ah[1], b1, acc, 0, 0, 0);
        acc = __builtin_amdgcn_mfma_f32_32x32x16_bf16(ah[2], b2, acc, 0, 0, 0);
        acc = __builtin_amdgcn_mfma_f32_32x32x16_bf16(ah[3], b3, acc, 0, 0, 0);
#pragma unroll
        for (int r = 0; r < 16; ++r) m[r] = fminf(m[r], fmaf(-2.f, acc[r], eA));
    }
    // butterfly min across 32 col-lanes, then fold per-point window -> threshold
#pragma unroll
    for (int r = 0; r < 16; ++r) {
        for (int d2 = 1; d2 <= 16; d2 <<= 1)
            m[r] = fminf(m[r], __shfl_xor(m[r], d2));
        m[r] += wp[wv * 32 + 4 * (lane >> 5) + (r & 3) + 8 * (r >> 2)];
    }

#define ENQ(PL, JJ) do {                                                  \
    unsigned _s = atomicAdd(&ccnt[PL], 1u);                               \
    if (_s < MAXC) cand[(PL) * MAXC + _s] = (unsigned short)(JJ);         \
    else { unsigned _o = atomicAdd(&oqcnt, 1u);                           \
           if (_o < OQCAP) oq[_o] = ((unsigned)(PL) << 16) | (JJ);        \
           else gflow = 1; }                                              \
} while (0)

    // ---- sweep 2: recompute (bit-identical), enqueue window hits
#pragma unroll 1
    for (int nt = 0; nt < 32; ++nt) {
        bf16x8 b0 = bB[(nt * 4 + 0) * 64 + lane];
        bf16x8 b1 = bB[(nt * 4 + 1) * 64 + lane];
        bf16x8 b2 = bB[(nt * 4 + 2) * 64 + lane];
        bf16x8 b3 = bB[(nt * 4 + 3) * 64 + lane];
        float eA = eeL[nt * 32 + (lane & 31)];
        f32x16 acc;
#pragma unroll
        for (int r = 0; r < 16; ++r) acc[r] = 0.f;
        acc = __builtin_amdgcn_mfma_f32_32x32x16_bf16(ah[0], b0, acc, 0, 0, 0);
        acc = __builtin_amdgcn_mfma_f32_32x32x16_bf16(ah[1], b1, acc, 0, 0, 0);
        acc = __builtin_amdgcn_mfma_f32_32x32x16_bf16(ah[2], b2, acc, 0, 0, 0);
        acc = __builtin_amdgcn_mfma_f32_32x32x16_bf16(ah[3], b3, acc, 0, 0, 0);
        unsigned jj = (unsigned)(nt * 32 + (lane & 31));
#pragma unroll
        for (int r = 0; r < 16; ++r) {
            bool hit = fmaf(-2.f, acc[r], eA) <= m[r];
            if (__any(hit)) {
                if (hit) {
                    int pl = wv * 32 + 4 * (lane >> 5) + (r & 3) + 8 * (r >> 2);
                    ENQ(pl, jj);
                }
            }
        }
    }
    __syncthreads();

    // ---- exact refine (z from global, L2-hot; ~1-3 candidates/point)
    if (gflow) {
        if (tid < 512) {                        // never-taken safety net
            unsigned long long bk = 0xFFFFFFFFFFFFFFFFull;
            for (int j = 0; j < NUM_E; ++j) {
                unsigned long long k2 = key_glob(zb, zzs[tid], eeL[j], cb, tid, j);
                if (k2 < bk) bk = k2;
            }
            best[tid] = bk;
        }
    } else {
        if (tid < 512) {
            int n = (int)ccnt[tid]; if (n > MAXC) n = MAXC;
            unsigned long long bk = 0xFFFFFFFFFFFFFFFFull;
            for (int e = 0; e < n; ++e) {
                int j = (int)cand[tid * MAXC + e];
                unsigned long long k2 = key_glob(zb, zzs[tid], eeL[j], cb, tid, j);
                if (k2 < bk) bk = k2;
            }
            atomicMin(&best[tid], bk);
        }
        int no = (int)oqcnt; if (no > OQCAP) no = OQCAP;
        for (int e = tid; e < no; e += 1024) {
            unsigned u = oq[e];
            int pl = (int)(u >> 16), j = (int)(u & 0xFFFFu);
            atomicMin(&best[pl], key_glob(zb, zzs[pl], eeL[j], cb, pl, j));
        }
    }
    __syncthreads();
    if (tid < 512) {
        int bi = (int)(best[tid] & 0xFFFFFFFFull);
        ibuf[tid] = bi;
        idx_f[(size_t)g * 512 + tid] = (float)bi;
        atomicAdd(&counts[bi], 1);
    }
    __syncthreads();

    // ---- fused tail: z_q_st = fl(z + fl(q - z)), float4 loads/stores; loss partial
    {
        int w4 = tid & 127, c8 = (tid >> 7) * 8;          // 128 pt-quads x 64 ch
        const float4* zb4 = (const float4*)zb;
        float4* zq4 = (float4*)(zq + zoff);
        size_t b0 = (size_t)ibuf[w4 * 4 + 0] << 6;
        size_t b1 = (size_t)ibuf[w4 * 4 + 1] << 6;
        size_t b2 = (size_t)ibuf[w4 * 4 + 2] << 6;
        size_t b3 = (size_t)ibuf[w4 * 4 + 3] << 6;
        double ls = 0.0;
#pragma unroll
        for (int i = 0; i < 8; ++i) {
            int c = c8 + i;
            float4 zv = zb4[(size_t)c * 1024 + w4];
            float q0 = cb[b0 + c], q1 = cb[b1 + c], q2 = cb[b2 + c], q3 = cb[b3 + c];
            float t0 = q0 - zv.x, t1 = q1 - zv.y, t2 = q2 - zv.z, t3 = q3 - zv.w;
            zq4[(size_t)c * 1024 + w4] =
                make_float4(zv.x + t0, zv.y + t1, zv.z + t2, zv.w + t3);
            ls += (double)t0 * t0 + (double)t1 * t1 + (double)t2 * t2 + (double)t3 * t3;
        }
#pragma unroll
        for (int off = 32; off > 0; off >>= 1) ls += __shfl_down(ls, off);
        if (lane == 0) wsum[wv] = ls;
    }
    __syncthreads();
    if (tid == 0) {
        double s = 0.0;
#pragma unroll
        for (int i = 0; i < 16; ++i) s += wsum[i];
        partials[g] = s;
    }
}

// ---------------------------------------------------------------- scalars
__global__ __launch_bounds__(256) void vq_final(
    const int* __restrict__ counts, const double* __restrict__ partials,
    float* __restrict__ scalars)
{
    __shared__ double sh[256];
    __shared__ double sl[256];
    int t = threadIdx.x;
    double s = 0.0;
    for (int j = t; j < NUM_E; j += 256) {
        float em   = (float)counts[j] * (1.0f / 131072.0f);
        float term = em * logf(em + 1e-10f);
        s += (double)term;
    }
    double l = 0.0;
#pragma unroll
    for (int j = 0; j < AGRID / 256; ++j) l += partials[j * 256 + t];
    sh[t] = s;
    sl[t] = l;
    __syncthreads();
    for (int off = 128; off > 0; off >>= 1) {
        if (t < off) { sh[t] += sh[t + off]; sl[t] += sl[t + off]; }
        __syncthreads();
    }
    if (t == 0) {
        float mm = (float)(sl[0] / 8388608.0);
        scalars[0] = mm + 0.5f * mm;         // mean1 + BETA*mean2
        scalars[1] = expf(-(float)sh[0]);    // perplexity
    }
}

// ---------------------------------------------------------------- launch
extern "C" void kernel_launch(void* const* d_in, const int* in_sizes, int n_in,
                              void* d_out, int out_size, void* d_ws, size_t ws_size,
                              hipStream_t stream)
{
    const float* z  = (const float*)d_in[0];
    const float* cb = (const float*)d_in[1];
    float* out     = (float*)d_out;
    float* zq      = out;                    // [32,64,64,64]
    float* scalars = out + ZQ_ELEM;          // loss, perplexity
    float* idx_f   = out + ZQ_ELEM + 2;      // [32,64,64] as float

    int*            counts   = (int*)d_ws;                             // 4 KB
    double*         partials = (double*)((char*)d_ws + 4096);          // 2 KB
    float*          ee       = (float*)((char*)d_ws + 12288);          // 4 KB
    unsigned short* ehi      = (unsigned short*)((char*)d_ws + 16384); // 128 KB

    hipMemsetAsync(d_ws, 0, 4096, stream);                    // zero counts
    vq_prep  <<<4,     256, 0, stream>>>(cb, ee, ehi);
    vq_argmin<<<AGRID, 1024, 0, stream>>>(z, cb, ehi, ee, idx_f, counts, zq, partials);
    vq_final <<<1,     256, 0, stream>>>(counts, partials, scalars);
}